// Round 3
// baseline (10176.231 us; speedup 1.0000x reference)
//
#include <hip/hip_runtime.h>
#include <hip/hip_bf16.h>

// Problem constants
#define NB   1024      // B rows
#define NN   65536     // candidates
#define NF   64        // input features
#define ND   512       // D
#define NDB  1024      // DB
#define NC   96        // context size

// GEMM tiling
#define BM 128
#define BN 128
#define BK 16

// Chunking (keeps total workspace ~225 MB)
#define CH_A 8192      // candidate-encode chunk rows
#define BB_C 256       // scores/topk chunk of B rows
#define BB_D 64        // values-path chunk of B rows

// ---------------------------------------------------------------------------
// Tiled GEMM: C = act(A[M,K] @ W[K,N] + bias) + res   (all f32)
// 128x128 tile, BK=16, 256 threads, 8x8 microtile.
// NOTE: res/C may alias (in-place residual) -> no __restrict__ on them.
// ---------------------------------------------------------------------------
__global__ __launch_bounds__(256, 2) void gemm_nn_kernel(
    const float* __restrict__ A, const float* __restrict__ W,
    const float* __restrict__ bias, const float* res,
    float* C, int M, int N, int K, int relu)
{
    __shared__ float As[BK][BM + 4];   // As[k][m]
    __shared__ float Bs[BK][BN + 4];   // Bs[k][n]

    const int tid = threadIdx.x;
    const int tn  = (tid & 15) * 8;
    const int tm  = (tid >> 4) * 8;
    const int row0 = blockIdx.y * BM;
    const int col0 = blockIdx.x * BN;

    float acc[8][8];
#pragma unroll
    for (int i = 0; i < 8; i++)
#pragma unroll
        for (int j = 0; j < 8; j++) acc[i][j] = 0.f;

    const int ar = tid >> 2;          // 0..63
    const int ac = (tid & 3) * 4;     // 0,4,8,12
    const int wr = tid >> 5;          // 0..7
    const int wc = (tid & 31) * 4;    // 0..124

    for (int k0 = 0; k0 < K; k0 += BK) {
        float4 a0 = *(const float4*)(A + (size_t)(row0 + ar) * K + k0 + ac);
        float4 a1 = *(const float4*)(A + (size_t)(row0 + ar + 64) * K + k0 + ac);
        float4 w0 = *(const float4*)(W + (size_t)(k0 + wr) * N + col0 + wc);
        float4 w1 = *(const float4*)(W + (size_t)(k0 + wr + 8) * N + col0 + wc);

        __syncthreads();
        As[ac + 0][ar] = a0.x; As[ac + 1][ar] = a0.y;
        As[ac + 2][ar] = a0.z; As[ac + 3][ar] = a0.w;
        As[ac + 0][ar + 64] = a1.x; As[ac + 1][ar + 64] = a1.y;
        As[ac + 2][ar + 64] = a1.z; As[ac + 3][ar + 64] = a1.w;
        *(float4*)&Bs[wr][wc]     = w0;
        *(float4*)&Bs[wr + 8][wc] = w1;
        __syncthreads();

#pragma unroll
        for (int kk = 0; kk < BK; kk++) {
            float a[8], b[8];
            *(float4*)&a[0] = *(const float4*)&As[kk][tm];
            *(float4*)&a[4] = *(const float4*)&As[kk][tm + 4];
            *(float4*)&b[0] = *(const float4*)&Bs[kk][tn];
            *(float4*)&b[4] = *(const float4*)&Bs[kk][tn + 4];
#pragma unroll
            for (int i = 0; i < 8; i++)
#pragma unroll
                for (int j = 0; j < 8; j++) acc[i][j] += a[i] * b[j];
        }
    }

    float bv[8];
#pragma unroll
    for (int j = 0; j < 8; j++) bv[j] = bias ? bias[col0 + tn + j] : 0.f;

#pragma unroll
    for (int i = 0; i < 8; i++) {
        const size_t base = (size_t)(row0 + tm + i) * N + col0 + tn;
#pragma unroll
        for (int j = 0; j < 8; j++) {
            float v = acc[i][j] + bv[j];
            if (res) v += res[base + j];
            if (relu) v = fmaxf(v, 0.f);
            C[base + j] = v;
        }
    }
}

// ---------------------------------------------------------------------------
// Values-path GEMM with fused diff gather:
// logical A row r (r = b_loc*NC + c): A[r,:] = kx[b_loc,:] - ck[idx[r]],:]
// C = relu(A @ W + bias)
// ---------------------------------------------------------------------------
__global__ __launch_bounds__(256, 2) void gemm_diff_kernel(
    const float* __restrict__ kx, const float* __restrict__ ck,
    const int* __restrict__ idx, const float* __restrict__ W,
    const float* __restrict__ bias, float* __restrict__ C,
    int M, int N, int K)
{
    __shared__ float As[BK][BM + 4];
    __shared__ float Bs[BK][BN + 4];

    const int tid = threadIdx.x;
    const int tn  = (tid & 15) * 8;
    const int tm  = (tid >> 4) * 8;
    const int row0 = blockIdx.y * BM;
    const int col0 = blockIdx.x * BN;

    float acc[8][8];
#pragma unroll
    for (int i = 0; i < 8; i++)
#pragma unroll
        for (int j = 0; j < 8; j++) acc[i][j] = 0.f;

    const int ar = tid >> 2;
    const int ac = (tid & 3) * 4;
    const int wr = tid >> 5;
    const int wc = (tid & 31) * 4;

    const int r0 = row0 + ar;
    const int r1 = r0 + 64;
    const int b0l = r0 / NC, c0l = r0 - b0l * NC;
    const int b1l = r1 / NC, c1l = r1 - b1l * NC;
    const float* kx0 = kx + (size_t)b0l * ND;
    const float* kx1 = kx + (size_t)b1l * ND;
    const float* ck0 = ck + (size_t)idx[b0l * NC + c0l] * ND;
    const float* ck1 = ck + (size_t)idx[b1l * NC + c1l] * ND;

    for (int k0 = 0; k0 < K; k0 += BK) {
        float4 p0 = *(const float4*)(kx0 + k0 + ac);
        float4 q0 = *(const float4*)(ck0 + k0 + ac);
        float4 p1 = *(const float4*)(kx1 + k0 + ac);
        float4 q1 = *(const float4*)(ck1 + k0 + ac);
        float4 w0 = *(const float4*)(W + (size_t)(k0 + wr) * N + col0 + wc);
        float4 w1 = *(const float4*)(W + (size_t)(k0 + wr + 8) * N + col0 + wc);

        __syncthreads();
        As[ac + 0][ar] = p0.x - q0.x; As[ac + 1][ar] = p0.y - q0.y;
        As[ac + 2][ar] = p0.z - q0.z; As[ac + 3][ar] = p0.w - q0.w;
        As[ac + 0][ar + 64] = p1.x - q1.x; As[ac + 1][ar + 64] = p1.y - q1.y;
        As[ac + 2][ar + 64] = p1.z - q1.z; As[ac + 3][ar + 64] = p1.w - q1.w;
        *(float4*)&Bs[wr][wc]     = w0;
        *(float4*)&Bs[wr + 8][wc] = w1;
        __syncthreads();

#pragma unroll
        for (int kk = 0; kk < BK; kk++) {
            float a[8], b[8];
            *(float4*)&a[0] = *(const float4*)&As[kk][tm];
            *(float4*)&a[4] = *(const float4*)&As[kk][tm + 4];
            *(float4*)&b[0] = *(const float4*)&Bs[kk][tn];
            *(float4*)&b[4] = *(const float4*)&Bs[kk][tn + 4];
#pragma unroll
            for (int i = 0; i < 8; i++)
#pragma unroll
                for (int j = 0; j < 8; j++) acc[i][j] += a[i] * b[j];
        }
    }

    float bv[8];
#pragma unroll
    for (int j = 0; j < 8; j++) bv[j] = bias[col0 + tn + j];

#pragma unroll
    for (int i = 0; i < 8; i++) {
        const size_t base = (size_t)(row0 + tm + i) * N + col0 + tn;
#pragma unroll
        for (int j = 0; j < 8; j++)
            C[base + j] = fmaxf(acc[i][j] + bv[j], 0.f);
    }
}

// ---------------------------------------------------------------------------
// Scores GEMM (A @ B^T epilogue): S[m,n] = sq[n] - 2 * sum_k A[m,k]*CK[n,k]
// (the +||k_m||^2 per-row term is topk/softmax-invariant and dropped)
// ---------------------------------------------------------------------------
__global__ __launch_bounds__(256, 2) void gemm_nt_scores_kernel(
    const float* __restrict__ A, const float* __restrict__ CK,
    const float* __restrict__ sq, float* __restrict__ S, int M, int N, int K)
{
    __shared__ float As[BK][BM + 4];
    __shared__ float Bs[BK][BN + 4];

    const int tid = threadIdx.x;
    const int tn  = (tid & 15) * 8;
    const int tm  = (tid >> 4) * 8;
    const int row0 = blockIdx.y * BM;
    const int col0 = blockIdx.x * BN;

    float acc[8][8];
#pragma unroll
    for (int i = 0; i < 8; i++)
#pragma unroll
        for (int j = 0; j < 8; j++) acc[i][j] = 0.f;

    const int ar = tid >> 2;
    const int ac = (tid & 3) * 4;

    for (int k0 = 0; k0 < K; k0 += BK) {
        float4 a0 = *(const float4*)(A + (size_t)(row0 + ar) * K + k0 + ac);
        float4 a1 = *(const float4*)(A + (size_t)(row0 + ar + 64) * K + k0 + ac);
        float4 b0 = *(const float4*)(CK + (size_t)(col0 + ar) * K + k0 + ac);
        float4 b1 = *(const float4*)(CK + (size_t)(col0 + ar + 64) * K + k0 + ac);

        __syncthreads();
        As[ac + 0][ar] = a0.x; As[ac + 1][ar] = a0.y;
        As[ac + 2][ar] = a0.z; As[ac + 3][ar] = a0.w;
        As[ac + 0][ar + 64] = a1.x; As[ac + 1][ar + 64] = a1.y;
        As[ac + 2][ar + 64] = a1.z; As[ac + 3][ar + 64] = a1.w;
        Bs[ac + 0][ar] = b0.x; Bs[ac + 1][ar] = b0.y;
        Bs[ac + 2][ar] = b0.z; Bs[ac + 3][ar] = b0.w;
        Bs[ac + 0][ar + 64] = b1.x; Bs[ac + 1][ar + 64] = b1.y;
        Bs[ac + 2][ar + 64] = b1.z; Bs[ac + 3][ar + 64] = b1.w;
        __syncthreads();

#pragma unroll
        for (int kk = 0; kk < BK; kk++) {
            float a[8], b[8];
            *(float4*)&a[0] = *(const float4*)&As[kk][tm];
            *(float4*)&a[4] = *(const float4*)&As[kk][tm + 4];
            *(float4*)&b[0] = *(const float4*)&Bs[kk][tn];
            *(float4*)&b[4] = *(const float4*)&Bs[kk][tn + 4];
#pragma unroll
            for (int i = 0; i < 8; i++)
#pragma unroll
                for (int j = 0; j < 8; j++) acc[i][j] += a[i] * b[j];
        }
    }

    float sv[8];
#pragma unroll
    for (int j = 0; j < 8; j++) sv[j] = sq[col0 + tn + j];

#pragma unroll
    for (int i = 0; i < 8; i++) {
        const size_t base = (size_t)(row0 + tm + i) * N + col0 + tn;
#pragma unroll
        for (int j = 0; j < 8; j++)
            S[base + j] = sv[j] - 2.f * acc[i][j];
    }
}

// ---------------------------------------------------------------------------
// LayerNorm over rows of 512 (one wave per row). relu flag for head LN.
// ---------------------------------------------------------------------------
__global__ __launch_bounds__(256) void ln_kernel(
    const float* __restrict__ X, const float* __restrict__ g,
    const float* __restrict__ b, float* __restrict__ Y, int relu)
{
    const int lane = threadIdx.x & 63;
    const int row  = blockIdx.x * 4 + (threadIdx.x >> 6);
    const float* x = X + (size_t)row * ND;
    const int d = lane * 8;

    float4 v0 = *(const float4*)(x + d);
    float4 v1 = *(const float4*)(x + d + 4);
    float s = v0.x + v0.y + v0.z + v0.w + v1.x + v1.y + v1.z + v1.w;
    float q = v0.x*v0.x + v0.y*v0.y + v0.z*v0.z + v0.w*v0.w
            + v1.x*v1.x + v1.y*v1.y + v1.z*v1.z + v1.w*v1.w;
#pragma unroll
    for (int off = 32; off; off >>= 1) {
        s += __shfl_down(s, off);
        q += __shfl_down(q, off);
    }
    s = __shfl(s, 0); q = __shfl(q, 0);
    const float mean = s * (1.f / ND);
    const float var  = q * (1.f / ND) - mean * mean;
    const float rs   = rsqrtf(var + 1e-5f);

    float4 g0 = *(const float4*)(g + d);
    float4 g1 = *(const float4*)(g + d + 4);
    float4 b0 = *(const float4*)(b + d);
    float4 b1 = *(const float4*)(b + d + 4);
    float4 o0, o1;
    o0.x = (v0.x - mean) * rs * g0.x + b0.x;
    o0.y = (v0.y - mean) * rs * g0.y + b0.y;
    o0.z = (v0.z - mean) * rs * g0.z + b0.z;
    o0.w = (v0.w - mean) * rs * g0.w + b0.w;
    o1.x = (v1.x - mean) * rs * g1.x + b1.x;
    o1.y = (v1.y - mean) * rs * g1.y + b1.y;
    o1.z = (v1.z - mean) * rs * g1.z + b1.z;
    o1.w = (v1.w - mean) * rs * g1.w + b1.w;
    if (relu) {
        o0.x = fmaxf(o0.x, 0.f); o0.y = fmaxf(o0.y, 0.f);
        o0.z = fmaxf(o0.z, 0.f); o0.w = fmaxf(o0.w, 0.f);
        o1.x = fmaxf(o1.x, 0.f); o1.y = fmaxf(o1.y, 0.f);
        o1.z = fmaxf(o1.z, 0.f); o1.w = fmaxf(o1.w, 0.f);
    }
    float* y = Y + (size_t)row * ND;
    *(float4*)(y + d)     = o0;
    *(float4*)(y + d + 4) = o1;
}

// ---------------------------------------------------------------------------
// Row squared-norm (one wave per row of 512)
// ---------------------------------------------------------------------------
__global__ __launch_bounds__(256) void sqnorm_kernel(
    const float* __restrict__ X, float* __restrict__ sq)
{
    const int lane = threadIdx.x & 63;
    const int row  = blockIdx.x * 4 + (threadIdx.x >> 6);
    const float* x = X + (size_t)row * ND;
    const int d = lane * 8;
    float4 v0 = *(const float4*)(x + d);
    float4 v1 = *(const float4*)(x + d + 4);
    float q = v0.x*v0.x + v0.y*v0.y + v0.z*v0.z + v0.w*v0.w
            + v1.x*v1.x + v1.y*v1.y + v1.z*v1.z + v1.w*v1.w;
#pragma unroll
    for (int off = 32; off; off >>= 1) q += __shfl_down(q, off);
    if (lane == 0) sq[row] = q;
}

// ---------------------------------------------------------------------------
// Exact top-96 smallest per row via 4-level byte radix select.
// S is a chunk of BB_C rows; global row = b0 + blockIdx.x.
// ---------------------------------------------------------------------------
__device__ __forceinline__ unsigned fkey(float f)
{
    unsigned u = __float_as_uint(f);
    return (u & 0x80000000u) ? ~u : (u | 0x80000000u);
}

__global__ __launch_bounds__(256) void topk_kernel(
    const float* __restrict__ S, int* __restrict__ idx_out,
    float* __restrict__ val_out, int b0)
{
    const int row = blockIdx.x;
    const int b = b0 + row;
    const float* srow = S + (size_t)row * NN;
    __shared__ unsigned hist[256];
    __shared__ unsigned sh_pref;
    __shared__ int sh_krem;
    __shared__ int cA, cB;
    const int tid = threadIdx.x;

    if (tid == 0) { sh_pref = 0u; sh_krem = NC; }
    __syncthreads();

    for (int level = 0; level < 4; level++) {
        const int shift = 24 - 8 * level;
        hist[tid] = 0u;
        __syncthreads();
        const unsigned pref  = sh_pref;
        const unsigned pmask = (level == 0) ? 0u : (0xFFFFFFFFu << (shift + 8));
        for (int i = tid; i < NN; i += 256) {
            unsigned u = fkey(srow[i]);
            if ((u & pmask) == pref)
                atomicAdd(&hist[(u >> shift) & 255u], 1u);
        }
        __syncthreads();
        if (tid == 0) {
            int krem = sh_krem;
            unsigned cum = 0;
            for (int bin = 0; bin < 256; bin++) {
                unsigned c = hist[bin];
                if (cum + c >= (unsigned)krem) {
                    sh_pref = pref | ((unsigned)bin << shift);
                    sh_krem = krem - (int)cum;
                    break;
                }
                cum += c;
            }
        }
        __syncthreads();
    }

    const unsigned T = sh_pref;
    const int need = sh_krem;
    const int cntLess = NC - need;
    if (tid == 0) { cA = 0; cB = 0; }
    __syncthreads();

    for (int i = tid; i < NN; i += 256) {
        unsigned u = fkey(srow[i]);
        if (u < T) {
            int p = atomicAdd(&cA, 1);
            idx_out[b * NC + p] = i;
            val_out[b * NC + p] = srow[i];
        } else if (u == T) {
            int p = atomicAdd(&cB, 1);
            if (p < need) {
                idx_out[b * NC + cntLess + p] = i;
                val_out[b * NC + cntLess + p] = srow[i];
            }
        }
    }
}

// ---------------------------------------------------------------------------
// probs = softmax over c of (-s_sel)
// ---------------------------------------------------------------------------
__global__ __launch_bounds__(128) void probs_kernel(
    const float* __restrict__ svals, float* __restrict__ probs)
{
    const int b = blockIdx.x;
    const int tid = threadIdx.x;
    __shared__ float red[128];
    const bool valid = tid < NC;
    float s = valid ? -svals[b * NC + tid] : -3.4e38f;
    red[tid] = s;
    __syncthreads();
#pragma unroll
    for (int off = 64; off; off >>= 1) {
        if (tid < off) red[tid] = fmaxf(red[tid], red[tid + off]);
        __syncthreads();
    }
    const float m = red[0];
    __syncthreads();
    float e = valid ? expf(s - m) : 0.f;
    red[tid] = e;
    __syncthreads();
#pragma unroll
    for (int off = 64; off; off >>= 1) {
        if (tid < off) red[tid] += red[tid + off];
        __syncthreads();
    }
    const float sum = red[0];
    if (valid) probs[b * NC + tid] = e / sum;
}

// ---------------------------------------------------------------------------
// ctx reduce (per-chunk): xout[b,:] = xin[b,:] + sum_c p[c]*VAL[b_loc,c,:]
//                                   + py*labW + labb
// ---------------------------------------------------------------------------
__global__ __launch_bounds__(256) void ctx_kernel(
    const float* __restrict__ VAL, const float* __restrict__ probs,
    const float* __restrict__ cand_y, const int* __restrict__ idx,
    const float* __restrict__ labW, const float* __restrict__ labb,
    const float* __restrict__ xin, float* __restrict__ xout, int b0)
{
    const int b_loc = blockIdx.x;
    const int b = b0 + b_loc;
    const int tid = threadIdx.x;
    __shared__ float pv[NC];
    __shared__ float red[256];
    float py_part = 0.f;
    if (tid < NC) {
        float p = probs[b * NC + tid];
        pv[tid] = p;
        py_part = p * cand_y[idx[b * NC + tid]];
    }
    red[tid] = py_part;
    __syncthreads();
#pragma unroll
    for (int off = 128; off; off >>= 1) {
        if (tid < off) red[tid] += red[tid + off];
        __syncthreads();
    }
    const float py = red[0];

    for (int d = tid; d < ND; d += 256) {
        const float* vp = VAL + (size_t)b_loc * NC * ND + d;
        float acc = 0.f;
#pragma unroll 8
        for (int c = 0; c < NC; c++) acc += pv[c] * vp[(size_t)c * ND];
        float ctx = acc + py * labW[d] + labb[d];
        xout[(size_t)b * ND + d] = xin[(size_t)b * ND + d] + ctx;
    }
}

// ---------------------------------------------------------------------------
// head: out[b] = dot(X[b,:], hW) + hb   (one wave per row)
// ---------------------------------------------------------------------------
__global__ __launch_bounds__(64) void head_kernel(
    const float* __restrict__ X, const float* __restrict__ hW,
    const float* __restrict__ hb, float* __restrict__ out)
{
    const int b = blockIdx.x;
    const int lane = threadIdx.x;
    const float* x = X + (size_t)b * ND;
    float acc = 0.f;
#pragma unroll
    for (int j = 0; j < 8; j++) {
        int d = lane + 64 * j;
        acc += x[d] * hW[d];
    }
#pragma unroll
    for (int off = 32; off; off >>= 1) acc += __shfl_down(acc, off);
    if (lane == 0) out[b] = acc + hb[0];
}

// ---------------------------------------------------------------------------
extern "C" void kernel_launch(void* const* d_in, const int* in_sizes, int n_in,
                              void* d_out, int out_size, void* d_ws, size_t ws_size,
                              hipStream_t stream)
{
    const float* x_num    = (const float*)d_in[0];
    const float* cand_num = (const float*)d_in[1];
    const float* cand_y   = (const float*)d_in[2];
    const float* lin_W    = (const float*)d_in[3];
    const float* lin_b    = (const float*)d_in[4];
    const float* e_W1     = (const float*)d_in[5];
    const float* e_b1     = (const float*)d_in[6];
    const float* e_W2     = (const float*)d_in[7];
    const float* e_b2     = (const float*)d_in[8];
    const float* mix_g    = (const float*)d_in[9];
    const float* mix_b    = (const float*)d_in[10];
    const float* K_W      = (const float*)d_in[11];
    const float* K_b      = (const float*)d_in[12];
    const float* lab_W    = (const float*)d_in[13];
    const float* lab_b    = (const float*)d_in[14];
    const float* T_W1     = (const float*)d_in[15];
    const float* T_b1     = (const float*)d_in[16];
    const float* T_W2     = (const float*)d_in[17];
    const float* p_ln_g   = (const float*)d_in[18];
    const float* p_ln_b   = (const float*)d_in[19];
    const float* p_W1     = (const float*)d_in[20];
    const float* p_b1     = (const float*)d_in[21];
    const float* p_W2     = (const float*)d_in[22];
    const float* p_b2     = (const float*)d_in[23];
    const float* h_ln_g   = (const float*)d_in[24];
    const float* h_ln_b   = (const float*)d_in[25];
    const float* h_W      = (const float*)d_in[26];
    const float* h_b      = (const float*)d_in[27];
    float* out = (float*)d_out;
    (void)in_sizes; (void)n_in; (void)out_size; (void)ws_size;

    // ---- workspace layout (f32; 256B-aligned regions; total ~225 MB) ----
    size_t off = 0;
    auto alloc = [&](size_t floats) -> float* {
        float* p = (float*)((char*)d_ws + off);
        off += ((floats * 4 + 255) / 256) * 256;
        return p;
    };
    float* R_CK  = alloc((size_t)NN * ND);        // cand_k (persistent), 134 MB
    float* R_sq  = alloc(NN);                     // ||cand_k||^2
    float* R_Hx  = alloc((size_t)NB * ND);        // x (encoder out)
    float* R_Tx  = alloc((size_t)NB * NDB);
    float* R_Gx  = alloc((size_t)NB * ND);
    float* R_kx  = alloc((size_t)NB * ND);        // k
    int*   R_idx = (int*)alloc((size_t)NB * NC);
    float* R_ssel= alloc((size_t)NB * NC);
    float* R_prob= alloc((size_t)NB * NC);
    float* R_xupd= alloc((size_t)NB * ND);
    float* R_lnx = alloc((size_t)NB * ND);
    float* R_tp  = alloc((size_t)NB * NDB);
    float* R_x2  = alloc((size_t)NB * ND);
    float* R_lnx2= alloc((size_t)NB * ND);
    // shared scratch: max(encode CH_A*1536=12.6M, scores BB_C*NN=16.8M,
    //                     values BB_D*NC*1536=9.4M) floats
    float* SCR   = alloc((size_t)BB_C * NN);      // 16.78 M floats = 67 MB

    auto gemm = [&](const float* A, const float* W, const float* bias,
                    const float* res, float* C, int M, int Nn, int K, int relu) {
        dim3 grid(Nn / BN, M / BM);
        hipLaunchKernelGGL(gemm_nn_kernel, grid, dim3(256), 0, stream,
                           A, W, bias, res, C, M, Nn, K, relu);
    };

    // ---- 1. candidate encode (chunked over N) ----
    for (int n0 = 0; n0 < NN; n0 += CH_A) {
        float* H = SCR;                         // [CH_A, 512]
        float* T = SCR + (size_t)CH_A * ND;     // [CH_A, 1024]; reused as G
        gemm(cand_num + (size_t)n0 * NF, lin_W, lin_b, nullptr, H, CH_A, ND, NF, 0);
        gemm(H, e_W1, e_b1, nullptr, T, CH_A, NDB, ND, 1);
        gemm(T, e_W2, e_b2, H, H, CH_A, ND, NDB, 0);
        hipLaunchKernelGGL(ln_kernel, dim3(CH_A / 4), dim3(256), 0, stream,
                           H, mix_g, mix_b, T, 0);   // G into T region
        gemm(T, K_W, K_b, nullptr, R_CK + (size_t)n0 * ND, CH_A, ND, ND, 0);
        hipLaunchKernelGGL(sqnorm_kernel, dim3(CH_A / 4), dim3(256), 0, stream,
                           R_CK + (size_t)n0 * ND, R_sq + n0);
    }

    // ---- 2. x encode ----
    gemm(x_num, lin_W, lin_b, nullptr, R_Hx, NB, ND, NF, 0);
    gemm(R_Hx, e_W1, e_b1, nullptr, R_Tx, NB, NDB, ND, 1);
    gemm(R_Tx, e_W2, e_b2, R_Hx, R_Hx, NB, ND, NDB, 0);
    hipLaunchKernelGGL(ln_kernel, dim3(NB / 4), dim3(256), 0, stream,
                       R_Hx, mix_g, mix_b, R_Gx, 0);
    gemm(R_Gx, K_W, K_b, nullptr, R_kx, NB, ND, ND, 0);

    // ---- 3. scores + top-96 (chunked over B) + softmax ----
    for (int b0 = 0; b0 < NB; b0 += BB_C) {
        hipLaunchKernelGGL(gemm_nt_scores_kernel, dim3(NN / BN, BB_C / BM),
                           dim3(256), 0, stream,
                           R_kx + (size_t)b0 * ND, R_CK, R_sq, SCR, BB_C, NN, ND);
        hipLaunchKernelGGL(topk_kernel, dim3(BB_C), dim3(256), 0, stream,
                           SCR, R_idx, R_ssel, b0);
    }
    hipLaunchKernelGGL(probs_kernel, dim3(NB), dim3(128), 0, stream, R_ssel, R_prob);

    // ---- 4. values path (chunked over B; diff fused into GEMM) ----
    for (int b0 = 0; b0 < NB; b0 += BB_D) {
        float* TT  = SCR;                               // [BB_D*96, 1024]
        float* VAL = SCR + (size_t)BB_D * NC * NDB;     // [BB_D*96, 512]
        const int M = BB_D * NC;   // 6144
        hipLaunchKernelGGL(gemm_diff_kernel, dim3(NDB / BN, M / BM), dim3(256),
                           0, stream,
                           R_kx + (size_t)b0 * ND, R_CK, R_idx + b0 * NC,
                           T_W1, T_b1, TT, M, NDB, ND);
        gemm(TT, T_W2, nullptr, nullptr, VAL, M, ND, NDB, 0);
        hipLaunchKernelGGL(ctx_kernel, dim3(BB_D), dim3(256), 0, stream,
                           VAL, R_prob, cand_y, R_idx, lab_W, lab_b,
                           R_Hx, R_xupd, b0);
    }

    // ---- 5. predictor block + head ----
    hipLaunchKernelGGL(ln_kernel, dim3(NB / 4), dim3(256), 0, stream,
                       R_xupd, p_ln_g, p_ln_b, R_lnx, 0);
    gemm(R_lnx, p_W1, p_b1, nullptr, R_tp, NB, NDB, ND, 1);
    gemm(R_tp, p_W2, p_b2, R_xupd, R_x2, NB, ND, NDB, 0);
    hipLaunchKernelGGL(ln_kernel, dim3(NB / 4), dim3(256), 0, stream,
                       R_x2, h_ln_g, h_ln_b, R_lnx2, 1);
    hipLaunchKernelGGL(head_kernel, dim3(NB), dim3(64), 0, stream,
                       R_lnx2, h_W, h_b, out);
}

// Round 4
// 5002.686 us; speedup vs baseline: 2.0342x; 2.0342x over previous
//
#include <hip/hip_runtime.h>

// Problem constants
#define NB   1024
#define NN   65536
#define NF   64
#define ND   512
#define NDB  1024
#define NC   96

// Chunking
#define CH_A 8192      // candidate-encode chunk rows
#define BB_C 256       // scores/topk chunk of B rows
#define BB_D 128       // values-path chunk of B rows

typedef __attribute__((ext_vector_type(8))) short short8;
typedef __attribute__((ext_vector_type(4))) float floatx4;

__device__ __forceinline__ unsigned short f2bf(float f) {   // RNE f32->bf16
    unsigned u = __float_as_uint(f);
    u += 0x7fffu + ((u >> 16) & 1u);
    return (unsigned short)(u >> 16);
}
__device__ __forceinline__ float bf2f(unsigned short h) {
    return __uint_as_float(((unsigned)h) << 16);
}
// LDS plane: [m][k] bf16, k-stride 32, 16B-chunk swizzle -> conflict-free frag reads
__device__ __forceinline__ int lds_off(int m, int c) {
    return m * 32 + (((c + (m >> 1)) & 3) << 3);
}
__device__ __forceinline__ void load16(const float* p, float* x) {
    *(float4*)(x)      = *(const float4*)(p);
    *(float4*)(x + 4)  = *(const float4*)(p + 4);
    *(float4*)(x + 8)  = *(const float4*)(p + 8);
    *(float4*)(x + 12) = *(const float4*)(p + 12);
}
__device__ __forceinline__ void write_split(const float* x, unsigned short* Ph,
                                            unsigned short* Pl, int m, int cp) {
    short8 h0, h1, l0, l1;
#pragma unroll
    for (int i = 0; i < 8; i++) {
        unsigned short h = f2bf(x[i]);
        h0[i] = (short)h;
        l0[i] = (short)f2bf(x[i] - bf2f(h));
        unsigned short g = f2bf(x[i + 8]);
        h1[i] = (short)g;
        l1[i] = (short)f2bf(x[i + 8] - bf2f(g));
    }
    *(short8*)(Ph + lds_off(m, cp))     = h0;
    *(short8*)(Ph + lds_off(m, cp + 1)) = h1;
    *(short8*)(Pl + lds_off(m, cp))     = l0;
    *(short8*)(Pl + lds_off(m, cp + 1)) = l1;
}
__device__ __forceinline__ void write_hi(const float* x, unsigned short* Ph, int m, int cp) {
    short8 h0, h1;
#pragma unroll
    for (int i = 0; i < 8; i++) {
        h0[i] = (short)f2bf(x[i]);
        h1[i] = (short)f2bf(x[i + 8]);
    }
    *(short8*)(Ph + lds_off(m, cp))     = h0;
    *(short8*)(Ph + lds_off(m, cp + 1)) = h1;
}

// ---------------------------------------------------------------------------
// Split-bf16 (f32-emulating) MFMA GEMM, NT: C = epi(A[M,K] @ BT[N,K]^T)
// epi: scoresq ? sq[n]-2*acc : relu?(acc+bias+res)
// ---------------------------------------------------------------------------
__global__ __launch_bounds__(256) void gemm_split_nt(
    const float* __restrict__ A, const float* __restrict__ BT,
    const float* __restrict__ bias, const float* res,
    const float* __restrict__ scoresq,
    float* C, int M, int N, int K, int relu)
{
    __shared__ unsigned short Ah[128 * 32], Al[128 * 32];
    __shared__ unsigned short Bh[128 * 32], Bl[128 * 32];
    const int tid = threadIdx.x;
    const int lane = tid & 63, wid = tid >> 6;
    const int wm = (wid & 1) * 64, wn = (wid >> 1) * 64;
    const int lane15 = lane & 15, quad = lane >> 4;
    const int row0 = blockIdx.y * 128, col0 = blockIdx.x * 128;
    const int sm = tid >> 1, scp = (tid & 1) * 2;

    const float* arow = A + (size_t)(row0 + sm) * K + scp * 8;
    const float* brow = BT + (size_t)(col0 + sm) * K + scp * 8;

    floatx4 acc[4][4];
#pragma unroll
    for (int i = 0; i < 4; i++)
#pragma unroll
        for (int j = 0; j < 4; j++) acc[i][j] = (floatx4){0.f, 0.f, 0.f, 0.f};

    for (int k0 = 0; k0 < K; k0 += 32) {
        float xa[16], xb[16];
        load16(arow + k0, xa);
        load16(brow + k0, xb);
        __syncthreads();
        write_split(xa, Ah, Al, sm, scp);
        write_split(xb, Bh, Bl, sm, scp);
        __syncthreads();

        short8 ah[4], al[4], bh[4], bl[4];
#pragma unroll
        for (int t = 0; t < 4; t++) {
            const int am = wm + t * 16 + lane15;
            const int bn = wn + t * 16 + lane15;
            ah[t] = *(const short8*)(Ah + lds_off(am, quad));
            al[t] = *(const short8*)(Al + lds_off(am, quad));
            bh[t] = *(const short8*)(Bh + lds_off(bn, quad));
            bl[t] = *(const short8*)(Bl + lds_off(bn, quad));
        }
#pragma unroll
        for (int i = 0; i < 4; i++)
#pragma unroll
            for (int j = 0; j < 4; j++) {
                acc[i][j] = __builtin_amdgcn_mfma_f32_16x16x32_bf16(ah[i], bh[j], acc[i][j], 0, 0, 0);
                acc[i][j] = __builtin_amdgcn_mfma_f32_16x16x32_bf16(ah[i], bl[j], acc[i][j], 0, 0, 0);
                acc[i][j] = __builtin_amdgcn_mfma_f32_16x16x32_bf16(al[i], bh[j], acc[i][j], 0, 0, 0);
            }
    }

    // epilogue: C/D layout col=lane&15, row=quad*4+reg  [m89]
#pragma unroll
    for (int i = 0; i < 4; i++)
#pragma unroll
        for (int j = 0; j < 4; j++) {
            const int gc = col0 + wn + j * 16 + lane15;
            const int rb = row0 + wm + i * 16 + quad * 4;
            const float bv = bias ? bias[gc] : 0.f;
            const float sv = scoresq ? scoresq[gc] : 0.f;
#pragma unroll
            for (int r = 0; r < 4; r++) {
                const size_t o = (size_t)(rb + r) * N + gc;
                float v = acc[i][j][r];
                if (scoresq) {
                    v = sv - 2.f * v;
                } else {
                    v += bv;
                    if (res) v += res[o];
                    if (relu) v = fmaxf(v, 0.f);
                }
                C[o] = v;
            }
        }
}

// ---------------------------------------------------------------------------
// Plain bf16 MFMA GEMM with fused diff gather (values MLP layer 1):
// row r: a = kx[r/96,:] - ck[idx[r],:];  TT[r,:] = bf16(relu(a @ BT^T + bias))
// ---------------------------------------------------------------------------
__global__ __launch_bounds__(256) void gemm_diff_bf16(
    const float* __restrict__ kx, const float* __restrict__ ck,
    const int* __restrict__ idx, const float* __restrict__ BT,
    const float* __restrict__ bias, unsigned short* __restrict__ TT,
    int M, int N, int K)
{
    __shared__ unsigned short Ah[128 * 32];
    __shared__ unsigned short Bh[128 * 32];
    const int tid = threadIdx.x;
    const int lane = tid & 63, wid = tid >> 6;
    const int wm = (wid & 1) * 64, wn = (wid >> 1) * 64;
    const int lane15 = lane & 15, quad = lane >> 4;
    const int row0 = blockIdx.y * 128, col0 = blockIdx.x * 128;
    const int sm = tid >> 1, scp = (tid & 1) * 2;

    const int r = row0 + sm;
    const int bidx = r / NC;
    const float* kxp = kx + (size_t)bidx * ND + scp * 8;
    const float* ckp = ck + (size_t)idx[r] * ND + scp * 8;
    const float* brow = BT + (size_t)(col0 + sm) * K + scp * 8;

    floatx4 acc[4][4];
#pragma unroll
    for (int i = 0; i < 4; i++)
#pragma unroll
        for (int j = 0; j < 4; j++) acc[i][j] = (floatx4){0.f, 0.f, 0.f, 0.f};

    for (int k0 = 0; k0 < K; k0 += 32) {
        float xa[16], xc[16], xb[16];
        load16(kxp + k0, xa);
        load16(ckp + k0, xc);
        load16(brow + k0, xb);
#pragma unroll
        for (int i = 0; i < 16; i++) xa[i] -= xc[i];
        __syncthreads();
        write_hi(xa, Ah, sm, scp);
        write_hi(xb, Bh, sm, scp);
        __syncthreads();

        short8 ah[4], bh[4];
#pragma unroll
        for (int t = 0; t < 4; t++) {
            ah[t] = *(const short8*)(Ah + lds_off(wm + t * 16 + lane15, quad));
            bh[t] = *(const short8*)(Bh + lds_off(wn + t * 16 + lane15, quad));
        }
#pragma unroll
        for (int i = 0; i < 4; i++)
#pragma unroll
            for (int j = 0; j < 4; j++)
                acc[i][j] = __builtin_amdgcn_mfma_f32_16x16x32_bf16(ah[i], bh[j], acc[i][j], 0, 0, 0);
    }

#pragma unroll
    for (int i = 0; i < 4; i++)
#pragma unroll
        for (int j = 0; j < 4; j++) {
            const int gc = col0 + wn + j * 16 + lane15;
            const int rb = row0 + wm + i * 16 + quad * 4;
            const float bv = bias[gc];
#pragma unroll
            for (int rr = 0; rr < 4; rr++) {
                const size_t o = (size_t)(rb + rr) * N + gc;
                TT[o] = f2bf(fmaxf(acc[i][j][rr] + bv, 0.f));
            }
        }
}

// ---------------------------------------------------------------------------
// Plain bf16 MFMA GEMM, A already bf16 [M][K]: C(f32) = A @ BT^T  (values layer 2)
// ---------------------------------------------------------------------------
__global__ __launch_bounds__(256) void gemm_bf16_f32(
    const unsigned short* __restrict__ A, const float* __restrict__ BT,
    float* __restrict__ C, int M, int N, int K)
{
    __shared__ unsigned short Ah[128 * 32];
    __shared__ unsigned short Bh[128 * 32];
    const int tid = threadIdx.x;
    const int lane = tid & 63, wid = tid >> 6;
    const int wm = (wid & 1) * 64, wn = (wid >> 1) * 64;
    const int lane15 = lane & 15, quad = lane >> 4;
    const int row0 = blockIdx.y * 128, col0 = blockIdx.x * 128;
    const int sm = tid >> 1, scp = (tid & 1) * 2;

    const unsigned short* arow = A + (size_t)(row0 + sm) * K + scp * 8;
    const float* brow = BT + (size_t)(col0 + sm) * K + scp * 8;

    floatx4 acc[4][4];
#pragma unroll
    for (int i = 0; i < 4; i++)
#pragma unroll
        for (int j = 0; j < 4; j++) acc[i][j] = (floatx4){0.f, 0.f, 0.f, 0.f};

    for (int k0 = 0; k0 < K; k0 += 32) {
        short8 a0 = *(const short8*)(arow + k0);
        short8 a1 = *(const short8*)(arow + k0 + 8);
        float xb[16];
        load16(brow + k0, xb);
        __syncthreads();
        *(short8*)(Ah + lds_off(sm, scp))     = a0;
        *(short8*)(Ah + lds_off(sm, scp + 1)) = a1;
        write_hi(xb, Bh, sm, scp);
        __syncthreads();

        short8 ah[4], bh[4];
#pragma unroll
        for (int t = 0; t < 4; t++) {
            ah[t] = *(const short8*)(Ah + lds_off(wm + t * 16 + lane15, quad));
            bh[t] = *(const short8*)(Bh + lds_off(wn + t * 16 + lane15, quad));
        }
#pragma unroll
        for (int i = 0; i < 4; i++)
#pragma unroll
            for (int j = 0; j < 4; j++)
                acc[i][j] = __builtin_amdgcn_mfma_f32_16x16x32_bf16(ah[i], bh[j], acc[i][j], 0, 0, 0);
    }

#pragma unroll
    for (int i = 0; i < 4; i++)
#pragma unroll
        for (int j = 0; j < 4; j++) {
            const int gc = col0 + wn + j * 16 + lane15;
            const int rb = row0 + wm + i * 16 + quad * 4;
#pragma unroll
            for (int rr = 0; rr < 4; rr++)
                C[(size_t)(rb + rr) * N + gc] = acc[i][j][rr];
        }
}

// ---------------------------------------------------------------------------
// Transpose W[K][N] -> WT[N][K] (f32, one-time prep)
// ---------------------------------------------------------------------------
__global__ __launch_bounds__(256) void transpose_kernel(
    const float* __restrict__ W, float* __restrict__ WT, int K, int N)
{
    const int o = blockIdx.x * 256 + threadIdx.x;
    if (o < K * N) {
        const int n = o / K, k = o - n * K;
        WT[o] = W[(size_t)k * N + n];
    }
}

// ---------------------------------------------------------------------------
// f32 vector GEMM (x-path / predictor only; small M)
// ---------------------------------------------------------------------------
#define BM 128
#define BN 128
#define BK 16
__global__ __launch_bounds__(256, 2) void gemm_nn_kernel(
    const float* __restrict__ A, const float* __restrict__ W,
    const float* __restrict__ bias, const float* res,
    float* C, int M, int N, int K, int relu)
{
    __shared__ float As[BK][BM + 4];
    __shared__ float Bs[BK][BN + 4];

    const int tid = threadIdx.x;
    const int tn  = (tid & 15) * 8;
    const int tm  = (tid >> 4) * 8;
    const int row0 = blockIdx.y * BM;
    const int col0 = blockIdx.x * BN;

    float acc[8][8];
#pragma unroll
    for (int i = 0; i < 8; i++)
#pragma unroll
        for (int j = 0; j < 8; j++) acc[i][j] = 0.f;

    const int ar = tid >> 2;
    const int ac = (tid & 3) * 4;
    const int wr = tid >> 5;
    const int wc = (tid & 31) * 4;

    for (int k0 = 0; k0 < K; k0 += BK) {
        float4 a0 = *(const float4*)(A + (size_t)(row0 + ar) * K + k0 + ac);
        float4 a1 = *(const float4*)(A + (size_t)(row0 + ar + 64) * K + k0 + ac);
        float4 w0 = *(const float4*)(W + (size_t)(k0 + wr) * N + col0 + wc);
        float4 w1 = *(const float4*)(W + (size_t)(k0 + wr + 8) * N + col0 + wc);

        __syncthreads();
        As[ac + 0][ar] = a0.x; As[ac + 1][ar] = a0.y;
        As[ac + 2][ar] = a0.z; As[ac + 3][ar] = a0.w;
        As[ac + 0][ar + 64] = a1.x; As[ac + 1][ar + 64] = a1.y;
        As[ac + 2][ar + 64] = a1.z; As[ac + 3][ar + 64] = a1.w;
        *(float4*)&Bs[wr][wc]     = w0;
        *(float4*)&Bs[wr + 8][wc] = w1;
        __syncthreads();

#pragma unroll
        for (int kk = 0; kk < BK; kk++) {
            float a[8], b[8];
            *(float4*)&a[0] = *(const float4*)&As[kk][tm];
            *(float4*)&a[4] = *(const float4*)&As[kk][tm + 4];
            *(float4*)&b[0] = *(const float4*)&Bs[kk][tn];
            *(float4*)&b[4] = *(const float4*)&Bs[kk][tn + 4];
#pragma unroll
            for (int i = 0; i < 8; i++)
#pragma unroll
                for (int j = 0; j < 8; j++) acc[i][j] += a[i] * b[j];
        }
    }

    float bv[8];
#pragma unroll
    for (int j = 0; j < 8; j++) bv[j] = bias ? bias[col0 + tn + j] : 0.f;

#pragma unroll
    for (int i = 0; i < 8; i++) {
        const size_t base = (size_t)(row0 + tm + i) * N + col0 + tn;
#pragma unroll
        for (int j = 0; j < 8; j++) {
            float v = acc[i][j] + bv[j];
            if (res) v += res[base + j];
            if (relu) v = fmaxf(v, 0.f);
            C[base + j] = v;
        }
    }
}

// ---------------------------------------------------------------------------
// LayerNorm rows of 512 (one wave per row)
// ---------------------------------------------------------------------------
__global__ __launch_bounds__(256) void ln_kernel(
    const float* __restrict__ X, const float* __restrict__ g,
    const float* __restrict__ b, float* __restrict__ Y, int relu)
{
    const int lane = threadIdx.x & 63;
    const int row  = blockIdx.x * 4 + (threadIdx.x >> 6);
    const float* x = X + (size_t)row * ND;
    const int d = lane * 8;

    float4 v0 = *(const float4*)(x + d);
    float4 v1 = *(const float4*)(x + d + 4);
    float s = v0.x + v0.y + v0.z + v0.w + v1.x + v1.y + v1.z + v1.w;
    float q = v0.x*v0.x + v0.y*v0.y + v0.z*v0.z + v0.w*v0.w
            + v1.x*v1.x + v1.y*v1.y + v1.z*v1.z + v1.w*v1.w;
#pragma unroll
    for (int off = 32; off; off >>= 1) {
        s += __shfl_down(s, off);
        q += __shfl_down(q, off);
    }
    s = __shfl(s, 0); q = __shfl(q, 0);
    const float mean = s * (1.f / ND);
    const float var  = q * (1.f / ND) - mean * mean;
    const float rs   = rsqrtf(var + 1e-5f);

    float4 g0 = *(const float4*)(g + d);
    float4 g1 = *(const float4*)(g + d + 4);
    float4 b0 = *(const float4*)(b + d);
    float4 b1 = *(const float4*)(b + d + 4);
    float4 o0, o1;
    o0.x = (v0.x - mean) * rs * g0.x + b0.x;
    o0.y = (v0.y - mean) * rs * g0.y + b0.y;
    o0.z = (v0.z - mean) * rs * g0.z + b0.z;
    o0.w = (v0.w - mean) * rs * g0.w + b0.w;
    o1.x = (v1.x - mean) * rs * g1.x + b1.x;
    o1.y = (v1.y - mean) * rs * g1.y + b1.y;
    o1.z = (v1.z - mean) * rs * g1.z + b1.z;
    o1.w = (v1.w - mean) * rs * g1.w + b1.w;
    if (relu) {
        o0.x = fmaxf(o0.x, 0.f); o0.y = fmaxf(o0.y, 0.f);
        o0.z = fmaxf(o0.z, 0.f); o0.w = fmaxf(o0.w, 0.f);
        o1.x = fmaxf(o1.x, 0.f); o1.y = fmaxf(o1.y, 0.f);
        o1.z = fmaxf(o1.z, 0.f); o1.w = fmaxf(o1.w, 0.f);
    }
    float* y = Y + (size_t)row * ND;
    *(float4*)(y + d)     = o0;
    *(float4*)(y + d + 4) = o1;
}

__global__ __launch_bounds__(256) void sqnorm_kernel(
    const float* __restrict__ X, float* __restrict__ sq)
{
    const int lane = threadIdx.x & 63;
    const int row  = blockIdx.x * 4 + (threadIdx.x >> 6);
    const float* x = X + (size_t)row * ND;
    const int d = lane * 8;
    float4 v0 = *(const float4*)(x + d);
    float4 v1 = *(const float4*)(x + d + 4);
    float q = v0.x*v0.x + v0.y*v0.y + v0.z*v0.z + v0.w*v0.w
            + v1.x*v1.x + v1.y*v1.y + v1.z*v1.z + v1.w*v1.w;
#pragma unroll
    for (int off = 32; off; off >>= 1) q += __shfl_down(q, off);
    if (lane == 0) sq[row] = q;
}

// ---------------------------------------------------------------------------
// Exact top-96 smallest per row via 4-level byte radix select
// ---------------------------------------------------------------------------
__device__ __forceinline__ unsigned fkey(float f)
{
    unsigned u = __float_as_uint(f);
    return (u & 0x80000000u) ? ~u : (u | 0x80000000u);
}

__global__ __launch_bounds__(256) void topk_kernel(
    const float* __restrict__ S, int* __restrict__ idx_out,
    float* __restrict__ val_out, int b0)
{
    const int row = blockIdx.x;
    const int b = b0 + row;
    const float* srow = S + (size_t)row * NN;
    __shared__ unsigned hist[256];
    __shared__ unsigned sh_pref;
    __shared__ int sh_krem;
    __shared__ int cA, cB;
    const int tid = threadIdx.x;

    if (tid == 0) { sh_pref = 0u; sh_krem = NC; }
    __syncthreads();

    for (int level = 0; level < 4; level++) {
        const int shift = 24 - 8 * level;
        hist[tid] = 0u;
        __syncthreads();
        const unsigned pref  = sh_pref;
        const unsigned pmask = (level == 0) ? 0u : (0xFFFFFFFFu << (shift + 8));
        for (int i = tid; i < NN; i += 256) {
            unsigned u = fkey(srow[i]);
            if ((u & pmask) == pref)
                atomicAdd(&hist[(u >> shift) & 255u], 1u);
        }
        __syncthreads();
        if (tid == 0) {
            int krem = sh_krem;
            unsigned cum = 0;
            for (int bin = 0; bin < 256; bin++) {
                unsigned c = hist[bin];
                if (cum + c >= (unsigned)krem) {
                    sh_pref = pref | ((unsigned)bin << shift);
                    sh_krem = krem - (int)cum;
                    break;
                }
                cum += c;
            }
        }
        __syncthreads();
    }

    const unsigned T = sh_pref;
    const int need = sh_krem;
    const int cntLess = NC - need;
    if (tid == 0) { cA = 0; cB = 0; }
    __syncthreads();

    for (int i = tid; i < NN; i += 256) {
        unsigned u = fkey(srow[i]);
        if (u < T) {
            int p = atomicAdd(&cA, 1);
            idx_out[b * NC + p] = i;
            val_out[b * NC + p] = srow[i];
        } else if (u == T) {
            int p = atomicAdd(&cB, 1);
            if (p < need) {
                idx_out[b * NC + cntLess + p] = i;
                val_out[b * NC + cntLess + p] = srow[i];
            }
        }
    }
}

__global__ __launch_bounds__(128) void probs_kernel(
    const float* __restrict__ svals, float* __restrict__ probs)
{
    const int b = blockIdx.x;
    const int tid = threadIdx.x;
    __shared__ float red[128];
    const bool valid = tid < NC;
    float s = valid ? -svals[b * NC + tid] : -3.4e38f;
    red[tid] = s;
    __syncthreads();
#pragma unroll
    for (int off = 64; off; off >>= 1) {
        if (tid < off) red[tid] = fmaxf(red[tid], red[tid + off]);
        __syncthreads();
    }
    const float m = red[0];
    __syncthreads();
    float e = valid ? expf(s - m) : 0.f;
    red[tid] = e;
    __syncthreads();
#pragma unroll
    for (int off = 64; off; off >>= 1) {
        if (tid < off) red[tid] += red[tid + off];
        __syncthreads();
    }
    const float sum = red[0];
    if (valid) probs[b * NC + tid] = e / sum;
}

__global__ __launch_bounds__(256) void ctx_kernel(
    const float* __restrict__ VAL, const float* __restrict__ probs,
    const float* __restrict__ cand_y, const int* __restrict__ idx,
    const float* __restrict__ labW, const float* __restrict__ labb,
    const float* __restrict__ xin, float* __restrict__ xout, int b0)
{
    const int b_loc = blockIdx.x;
    const int b = b0 + b_loc;
    const int tid = threadIdx.x;
    __shared__ float pv[NC];
    __shared__ float red[256];
    float py_part = 0.f;
    if (tid < NC) {
        float p = probs[b * NC + tid];
        pv[tid] = p;
        py_part = p * cand_y[idx[b * NC + tid]];
    }
    red[tid] = py_part;
    __syncthreads();
#pragma unroll
    for (int off = 128; off; off >>= 1) {
        if (tid < off) red[tid] += red[tid + off];
        __syncthreads();
    }
    const float py = red[0];

    for (int d = tid; d < ND; d += 256) {
        const float* vp = VAL + (size_t)b_loc * NC * ND + d;
        float acc = 0.f;
#pragma unroll 8
        for (int c = 0; c < NC; c++) acc += pv[c] * vp[(size_t)c * ND];
        float ctx = acc + py * labW[d] + labb[d];
        xout[(size_t)b * ND + d] = xin[(size_t)b * ND + d] + ctx;
    }
}

__global__ __launch_bounds__(64) void head_kernel(
    const float* __restrict__ X, const float* __restrict__ hW,
    const float* __restrict__ hb, float* __restrict__ out)
{
    const int b = blockIdx.x;
    const int lane = threadIdx.x;
    const float* x = X + (size_t)b * ND;
    float acc = 0.f;
#pragma unroll
    for (int j = 0; j < 8; j++) {
        int d = lane + 64 * j;
        acc += x[d] * hW[d];
    }
#pragma unroll
    for (int off = 32; off; off >>= 1) acc += __shfl_down(acc, off);
    if (lane == 0) out[b] = acc + hb[0];
}

// ---------------------------------------------------------------------------
extern "C" void kernel_launch(void* const* d_in, const int* in_sizes, int n_in,
                              void* d_out, int out_size, void* d_ws, size_t ws_size,
                              hipStream_t stream)
{
    const float* x_num    = (const float*)d_in[0];
    const float* cand_num = (const float*)d_in[1];
    const float* cand_y   = (const float*)d_in[2];
    const float* lin_W    = (const float*)d_in[3];
    const float* lin_b    = (const float*)d_in[4];
    const float* e_W1     = (const float*)d_in[5];
    const float* e_b1     = (const float*)d_in[6];
    const float* e_W2     = (const float*)d_in[7];
    const float* e_b2     = (const float*)d_in[8];
    const float* mix_g    = (const float*)d_in[9];
    const float* mix_b    = (const float*)d_in[10];
    const float* K_W      = (const float*)d_in[11];
    const float* K_b      = (const float*)d_in[12];
    const float* lab_W    = (const float*)d_in[13];
    const float* lab_b    = (const float*)d_in[14];
    const float* T_W1     = (const float*)d_in[15];
    const float* T_b1     = (const float*)d_in[16];
    const float* T_W2     = (const float*)d_in[17];
    const float* p_ln_g   = (const float*)d_in[18];
    const float* p_ln_b   = (const float*)d_in[19];
    const float* p_W1     = (const float*)d_in[20];
    const float* p_b1     = (const float*)d_in[21];
    const float* p_W2     = (const float*)d_in[22];
    const float* p_b2     = (const float*)d_in[23];
    const float* h_ln_g   = (const float*)d_in[24];
    const float* h_ln_b   = (const float*)d_in[25];
    const float* h_W      = (const float*)d_in[26];
    const float* h_b      = (const float*)d_in[27];
    float* out = (float*)d_out;
    (void)in_sizes; (void)n_in; (void)out_size; (void)ws_size;

    // ---- workspace layout (~236 MB) ----
    size_t off = 0;
    auto alloc = [&](size_t floats) -> float* {
        float* p = (float*)((char*)d_ws + off);
        off += ((floats * 4 + 255) / 256) * 256;
        return p;
    };
    // transposed weights [N][K] f32
    float* WT_lin = alloc((size_t)ND * NF);
    float* WT_e1  = alloc((size_t)NDB * ND);
    float* WT_e2  = alloc((size_t)ND * NDB);
    float* WT_kw  = alloc((size_t)ND * ND);
    float* WT_t1  = alloc((size_t)NDB * ND);
    float* WT_t2  = alloc((size_t)ND * NDB);

    float* R_CK  = alloc((size_t)NN * ND);        // cand_k (persistent)
    float* R_sq  = alloc(NN);
    float* R_Hx  = alloc((size_t)NB * ND);
    float* R_Tx  = alloc((size_t)NB * NDB);
    float* R_Gx  = alloc((size_t)NB * ND);
    float* R_kx  = alloc((size_t)NB * ND);
    int*   R_idx = (int*)alloc((size_t)NB * NC);
    float* R_ssel= alloc((size_t)NB * NC);
    float* R_prob= alloc((size_t)NB * NC);
    float* R_xupd= alloc((size_t)NB * ND);
    float* R_lnx = alloc((size_t)NB * ND);
    float* R_tp  = alloc((size_t)NB * NDB);
    float* R_x2  = alloc((size_t)NB * ND);
    float* R_lnx2= alloc((size_t)NB * ND);
    float* SCR   = alloc((size_t)BB_C * NN);      // 67 MB shared scratch

    // ---- 0. transpose weights ----
    auto tr = [&](const float* W, float* WT, int K, int N) {
        transpose_kernel<<<dim3((K * N + 255) / 256), dim3(256), 0, stream>>>(W, WT, K, N);
    };
    tr(lin_W, WT_lin, NF, ND);
    tr(e_W1,  WT_e1,  ND, NDB);
    tr(e_W2,  WT_e2,  NDB, ND);
    tr(K_W,   WT_kw,  ND, ND);
    tr(T_W1,  WT_t1,  ND, NDB);
    tr(T_W2,  WT_t2,  NDB, ND);

    auto gsplit = [&](const float* A, const float* BT, const float* bias,
                      const float* res, const float* sq, float* C,
                      int M, int Nn, int K, int relu) {
        gemm_split_nt<<<dim3(Nn / 128, M / 128), dim3(256), 0, stream>>>(
            A, BT, bias, res, sq, C, M, Nn, K, relu);
    };
    auto gf32 = [&](const float* A, const float* W, const float* bias,
                    const float* res, float* C, int M, int Nn, int K, int relu) {
        gemm_nn_kernel<<<dim3(Nn / BN, M / BM), dim3(256), 0, stream>>>(
            A, W, bias, res, C, M, Nn, K, relu);
    };

    // ---- 1. candidate encode (chunked, split-bf16 MFMA) ----
    for (int n0 = 0; n0 < NN; n0 += CH_A) {
        float* H = SCR;                          // [CH_A, 512]
        float* T = SCR + (size_t)CH_A * ND;      // [CH_A, 1024]; reused as G
        gsplit(cand_num + (size_t)n0 * NF, WT_lin, lin_b, nullptr, nullptr, H, CH_A, ND, NF, 0);
        gsplit(H, WT_e1, e_b1, nullptr, nullptr, T, CH_A, NDB, ND, 1);
        gsplit(T, WT_e2, e_b2, H, nullptr, H, CH_A, ND, NDB, 0);
        ln_kernel<<<dim3(CH_A / 4), dim3(256), 0, stream>>>(H, mix_g, mix_b, T, 0);
        gsplit(T, WT_kw, K_b, nullptr, nullptr, R_CK + (size_t)n0 * ND, CH_A, ND, ND, 0);
        sqnorm_kernel<<<dim3(CH_A / 4), dim3(256), 0, stream>>>(
            R_CK + (size_t)n0 * ND, R_sq + n0);
    }

    // ---- 2. x encode (f32 exact) ----
    gf32(x_num, lin_W, lin_b, nullptr, R_Hx, NB, ND, NF, 0);
    gf32(R_Hx, e_W1, e_b1, nullptr, R_Tx, NB, NDB, ND, 1);
    gf32(R_Tx, e_W2, e_b2, R_Hx, R_Hx, NB, ND, NDB, 0);
    ln_kernel<<<dim3(NB / 4), dim3(256), 0, stream>>>(R_Hx, mix_g, mix_b, R_Gx, 0);
    gf32(R_Gx, K_W, K_b, nullptr, R_kx, NB, ND, ND, 0);

    // ---- 3. scores (split-bf16 MFMA) + top-96 + softmax ----
    for (int b0 = 0; b0 < NB; b0 += BB_C) {
        gsplit(R_kx + (size_t)b0 * ND, R_CK, nullptr, nullptr, R_sq, SCR,
               BB_C, NN, ND, 0);
        topk_kernel<<<dim3(BB_C), dim3(256), 0, stream>>>(SCR, R_idx, R_ssel, b0);
    }
    probs_kernel<<<dim3(NB), dim3(128), 0, stream>>>(R_ssel, R_prob);

    // ---- 4. values path (plain bf16 MFMA, diff fused) ----
    for (int b0 = 0; b0 < NB; b0 += BB_D) {
        unsigned short* TT = (unsigned short*)SCR;               // [M,1024] bf16
        float* VAL = SCR + (size_t)BB_D * NC * NDB / 2 + 64;     // f32 after TT
        const int M = BB_D * NC;   // 12288
        gemm_diff_bf16<<<dim3(NDB / 128, M / 128), dim3(256), 0, stream>>>(
            R_kx + (size_t)b0 * ND, R_CK, R_idx + b0 * NC, WT_t1, T_b1,
            TT, M, NDB, ND);
        gemm_bf16_f32<<<dim3(ND / 128, M / 128), dim3(256), 0, stream>>>(
            TT, WT_t2, VAL, M, ND, NDB);
        ctx_kernel<<<dim3(BB_D), dim3(256), 0, stream>>>(
            VAL, R_prob, cand_y, R_idx, lab_W, lab_b, R_Hx, R_xupd, b0);
    }

    // ---- 5. predictor block + head (f32 exact) ----
    ln_kernel<<<dim3(NB / 4), dim3(256), 0, stream>>>(R_xupd, p_ln_g, p_ln_b, R_lnx, 0);
    gf32(R_lnx, p_W1, p_b1, nullptr, R_tp, NB, NDB, ND, 1);
    gf32(R_tp, p_W2, p_b2, R_xupd, R_x2, NB, ND, NDB, 0);
    ln_kernel<<<dim3(NB / 4), dim3(256), 0, stream>>>(R_x2, h_ln_g, h_ln_b, R_lnx2, 1);
    head_kernel<<<dim3(NB), dim3(64), 0, stream>>>(R_lnx2, h_W, h_b, out);
}

// Round 5
// 3657.235 us; speedup vs baseline: 2.7825x; 1.3679x over previous
//
#include <hip/hip_runtime.h>

// Problem constants
#define NB   1024
#define NN   65536
#define NF   64
#define ND   512
#define NDB  1024
#define NC   96

// Chunking
#define CH_A 8192      // candidate-encode chunk rows
#define BB_C 256       // scores/topk chunk of B rows
#define BB_D 128       // values-path chunk of B rows

// top-k parallelization
#define TK_SPLIT 16
#define TK_SEG   (NN / TK_SPLIT)   // 4096

typedef __attribute__((ext_vector_type(8))) short short8;
typedef __attribute__((ext_vector_type(4))) float floatx4;

__device__ __forceinline__ unsigned short f2bf(float f) {   // RNE f32->bf16
    unsigned u = __float_as_uint(f);
    u += 0x7fffu + ((u >> 16) & 1u);
    return (unsigned short)(u >> 16);
}
__device__ __forceinline__ float bf2f(unsigned short h) {
    return __uint_as_float(((unsigned)h) << 16);
}
// LDS plane: [m][k] bf16, k-stride 32, 16B-chunk swizzle -> conflict-free frag reads
__device__ __forceinline__ int lds_off(int m, int c) {
    return m * 32 + (((c + (m >> 1)) & 3) << 3);
}
__device__ __forceinline__ void load16(const float* p, float* x) {
    *(float4*)(x)      = *(const float4*)(p);
    *(float4*)(x + 4)  = *(const float4*)(p + 4);
    *(float4*)(x + 8)  = *(const float4*)(p + 8);
    *(float4*)(x + 12) = *(const float4*)(p + 12);
}
__device__ __forceinline__ void write_split(const float* x, unsigned short* Ph,
                                            unsigned short* Pl, int m, int cp) {
    short8 h0, h1, l0, l1;
#pragma unroll
    for (int i = 0; i < 8; i++) {
        unsigned short h = f2bf(x[i]);
        h0[i] = (short)h;
        l0[i] = (short)f2bf(x[i] - bf2f(h));
        unsigned short g = f2bf(x[i + 8]);
        h1[i] = (short)g;
        l1[i] = (short)f2bf(x[i + 8] - bf2f(g));
    }
    *(short8*)(Ph + lds_off(m, cp))     = h0;
    *(short8*)(Ph + lds_off(m, cp + 1)) = h1;
    *(short8*)(Pl + lds_off(m, cp))     = l0;
    *(short8*)(Pl + lds_off(m, cp + 1)) = l1;
}
__device__ __forceinline__ void write_hi(const float* x, unsigned short* Ph, int m, int cp) {
    short8 h0, h1;
#pragma unroll
    for (int i = 0; i < 8; i++) {
        h0[i] = (short)f2bf(x[i]);
        h1[i] = (short)f2bf(x[i + 8]);
    }
    *(short8*)(Ph + lds_off(m, cp))     = h0;
    *(short8*)(Ph + lds_off(m, cp + 1)) = h1;
}

// ---------------------------------------------------------------------------
// Split-bf16 (f32-emulating) MFMA GEMM, NT: C = epi(A[M,K] @ BT[N,K]^T)
// epi: scoresq ? sq[n]-2*acc : relu?(acc+bias+res)
// ---------------------------------------------------------------------------
__global__ __launch_bounds__(256) void gemm_split_nt(
    const float* __restrict__ A, const float* __restrict__ BT,
    const float* __restrict__ bias, const float* res,
    const float* __restrict__ scoresq,
    float* C, int M, int N, int K, int relu)
{
    __shared__ unsigned short Ah[128 * 32], Al[128 * 32];
    __shared__ unsigned short Bh[128 * 32], Bl[128 * 32];
    const int tid = threadIdx.x;
    const int lane = tid & 63, wid = tid >> 6;
    const int wm = (wid & 1) * 64, wn = (wid >> 1) * 64;
    const int lane15 = lane & 15, quad = lane >> 4;
    const int row0 = blockIdx.y * 128, col0 = blockIdx.x * 128;
    const int sm = tid >> 1, scp = (tid & 1) * 2;

    const float* arow = A + (size_t)(row0 + sm) * K + scp * 8;
    const float* brow = BT + (size_t)(col0 + sm) * K + scp * 8;

    floatx4 acc[4][4];
#pragma unroll
    for (int i = 0; i < 4; i++)
#pragma unroll
        for (int j = 0; j < 4; j++) acc[i][j] = (floatx4){0.f, 0.f, 0.f, 0.f};

    for (int k0 = 0; k0 < K; k0 += 32) {
        float xa[16], xb[16];
        load16(arow + k0, xa);
        load16(brow + k0, xb);
        __syncthreads();
        write_split(xa, Ah, Al, sm, scp);
        write_split(xb, Bh, Bl, sm, scp);
        __syncthreads();

        short8 ah[4], al[4], bh[4], bl[4];
#pragma unroll
        for (int t = 0; t < 4; t++) {
            const int am = wm + t * 16 + lane15;
            const int bn = wn + t * 16 + lane15;
            ah[t] = *(const short8*)(Ah + lds_off(am, quad));
            al[t] = *(const short8*)(Al + lds_off(am, quad));
            bh[t] = *(const short8*)(Bh + lds_off(bn, quad));
            bl[t] = *(const short8*)(Bl + lds_off(bn, quad));
        }
#pragma unroll
        for (int i = 0; i < 4; i++)
#pragma unroll
            for (int j = 0; j < 4; j++) {
                acc[i][j] = __builtin_amdgcn_mfma_f32_16x16x32_bf16(ah[i], bh[j], acc[i][j], 0, 0, 0);
                acc[i][j] = __builtin_amdgcn_mfma_f32_16x16x32_bf16(ah[i], bl[j], acc[i][j], 0, 0, 0);
                acc[i][j] = __builtin_amdgcn_mfma_f32_16x16x32_bf16(al[i], bh[j], acc[i][j], 0, 0, 0);
            }
    }

    // epilogue: C/D layout col=lane&15, row=quad*4+reg  [m89]
#pragma unroll
    for (int i = 0; i < 4; i++)
#pragma unroll
        for (int j = 0; j < 4; j++) {
            const int gc = col0 + wn + j * 16 + lane15;
            const int rb = row0 + wm + i * 16 + quad * 4;
            const float bv = bias ? bias[gc] : 0.f;
            const float sv = scoresq ? scoresq[gc] : 0.f;
#pragma unroll
            for (int r = 0; r < 4; r++) {
                const size_t o = (size_t)(rb + r) * N + gc;
                float v = acc[i][j][r];
                if (scoresq) {
                    v = sv - 2.f * v;
                } else {
                    v += bv;
                    if (res) v += res[o];
                    if (relu) v = fmaxf(v, 0.f);
                }
                C[o] = v;
            }
        }
}

// ---------------------------------------------------------------------------
// Plain bf16 MFMA GEMM with fused diff gather (values MLP layer 1)
// ---------------------------------------------------------------------------
__global__ __launch_bounds__(256) void gemm_diff_bf16(
    const float* __restrict__ kx, const float* __restrict__ ck,
    const int* __restrict__ idx, const float* __restrict__ BT,
    const float* __restrict__ bias, unsigned short* __restrict__ TT,
    int M, int N, int K)
{
    __shared__ unsigned short Ah[128 * 32];
    __shared__ unsigned short Bh[128 * 32];
    const int tid = threadIdx.x;
    const int lane = tid & 63, wid = tid >> 6;
    const int wm = (wid & 1) * 64, wn = (wid >> 1) * 64;
    const int lane15 = lane & 15, quad = lane >> 4;
    const int row0 = blockIdx.y * 128, col0 = blockIdx.x * 128;
    const int sm = tid >> 1, scp = (tid & 1) * 2;

    const int r = row0 + sm;
    const int bidx = r / NC;
    const float* kxp = kx + (size_t)bidx * ND + scp * 8;
    const float* ckp = ck + (size_t)idx[r] * ND + scp * 8;
    const float* brow = BT + (size_t)(col0 + sm) * K + scp * 8;

    floatx4 acc[4][4];
#pragma unroll
    for (int i = 0; i < 4; i++)
#pragma unroll
        for (int j = 0; j < 4; j++) acc[i][j] = (floatx4){0.f, 0.f, 0.f, 0.f};

    for (int k0 = 0; k0 < K; k0 += 32) {
        float xa[16], xc[16], xb[16];
        load16(kxp + k0, xa);
        load16(ckp + k0, xc);
        load16(brow + k0, xb);
#pragma unroll
        for (int i = 0; i < 16; i++) xa[i] -= xc[i];
        __syncthreads();
        write_hi(xa, Ah, sm, scp);
        write_hi(xb, Bh, sm, scp);
        __syncthreads();

        short8 ah[4], bh[4];
#pragma unroll
        for (int t = 0; t < 4; t++) {
            ah[t] = *(const short8*)(Ah + lds_off(wm + t * 16 + lane15, quad));
            bh[t] = *(const short8*)(Bh + lds_off(wn + t * 16 + lane15, quad));
        }
#pragma unroll
        for (int i = 0; i < 4; i++)
#pragma unroll
            for (int j = 0; j < 4; j++)
                acc[i][j] = __builtin_amdgcn_mfma_f32_16x16x32_bf16(ah[i], bh[j], acc[i][j], 0, 0, 0);
    }

#pragma unroll
    for (int i = 0; i < 4; i++)
#pragma unroll
        for (int j = 0; j < 4; j++) {
            const int gc = col0 + wn + j * 16 + lane15;
            const int rb = row0 + wm + i * 16 + quad * 4;
            const float bv = bias[gc];
#pragma unroll
            for (int rr = 0; rr < 4; rr++) {
                const size_t o = (size_t)(rb + rr) * N + gc;
                TT[o] = f2bf(fmaxf(acc[i][j][rr] + bv, 0.f));
            }
        }
}

// ---------------------------------------------------------------------------
// Plain bf16 MFMA GEMM, A bf16 [M][K]: C(f32) = A @ BT^T  (values layer 2)
// ---------------------------------------------------------------------------
__global__ __launch_bounds__(256) void gemm_bf16_f32(
    const unsigned short* __restrict__ A, const float* __restrict__ BT,
    float* __restrict__ C, int M, int N, int K)
{
    __shared__ unsigned short Ah[128 * 32];
    __shared__ unsigned short Bh[128 * 32];
    const int tid = threadIdx.x;
    const int lane = tid & 63, wid = tid >> 6;
    const int wm = (wid & 1) * 64, wn = (wid >> 1) * 64;
    const int lane15 = lane & 15, quad = lane >> 4;
    const int row0 = blockIdx.y * 128, col0 = blockIdx.x * 128;
    const int sm = tid >> 1, scp = (tid & 1) * 2;

    const unsigned short* arow = A + (size_t)(row0 + sm) * K + scp * 8;
    const float* brow = BT + (size_t)(col0 + sm) * K + scp * 8;

    floatx4 acc[4][4];
#pragma unroll
    for (int i = 0; i < 4; i++)
#pragma unroll
        for (int j = 0; j < 4; j++) acc[i][j] = (floatx4){0.f, 0.f, 0.f, 0.f};

    for (int k0 = 0; k0 < 1024; k0 += 32) {
        short8 a0 = *(const short8*)(arow + k0);
        short8 a1 = *(const short8*)(arow + k0 + 8);
        float xb[16];
        load16(brow + k0, xb);
        __syncthreads();
        *(short8*)(Ah + lds_off(sm, scp))     = a0;
        *(short8*)(Ah + lds_off(sm, scp + 1)) = a1;
        write_hi(xb, Bh, sm, scp);
        __syncthreads();

        short8 ah[4], bh[4];
#pragma unroll
        for (int t = 0; t < 4; t++) {
            ah[t] = *(const short8*)(Ah + lds_off(wm + t * 16 + lane15, quad));
            bh[t] = *(const short8*)(Bh + lds_off(wn + t * 16 + lane15, quad));
        }
#pragma unroll
        for (int i = 0; i < 4; i++)
#pragma unroll
            for (int j = 0; j < 4; j++)
                acc[i][j] = __builtin_amdgcn_mfma_f32_16x16x32_bf16(ah[i], bh[j], acc[i][j], 0, 0, 0);
    }

#pragma unroll
    for (int i = 0; i < 4; i++)
#pragma unroll
        for (int j = 0; j < 4; j++) {
            const int gc = col0 + wn + j * 16 + lane15;
            const int rb = row0 + wm + i * 16 + quad * 4;
#pragma unroll
            for (int rr = 0; rr < 4; rr++)
                C[(size_t)(rb + rr) * N + gc] = acc[i][j][rr];
        }
}

// ---------------------------------------------------------------------------
// Transpose W[K][N] -> WT[N][K] (one-time prep)
// ---------------------------------------------------------------------------
__global__ __launch_bounds__(256) void transpose_kernel(
    const float* __restrict__ W, float* __restrict__ WT, int K, int N)
{
    const int o = blockIdx.x * 256 + threadIdx.x;
    if (o < K * N) {
        const int n = o / K, k = o - n * K;
        WT[o] = W[(size_t)k * N + n];
    }
}

// ---------------------------------------------------------------------------
// LayerNorm rows of 512 (one wave per row)
// ---------------------------------------------------------------------------
__global__ __launch_bounds__(256) void ln_kernel(
    const float* __restrict__ X, const float* __restrict__ g,
    const float* __restrict__ b, float* __restrict__ Y, int relu)
{
    const int lane = threadIdx.x & 63;
    const int row  = blockIdx.x * 4 + (threadIdx.x >> 6);
    const float* x = X + (size_t)row * ND;
    const int d = lane * 8;

    float4 v0 = *(const float4*)(x + d);
    float4 v1 = *(const float4*)(x + d + 4);
    float s = v0.x + v0.y + v0.z + v0.w + v1.x + v1.y + v1.z + v1.w;
    float q = v0.x*v0.x + v0.y*v0.y + v0.z*v0.z + v0.w*v0.w
            + v1.x*v1.x + v1.y*v1.y + v1.z*v1.z + v1.w*v1.w;
#pragma unroll
    for (int off = 32; off; off >>= 1) {
        s += __shfl_down(s, off);
        q += __shfl_down(q, off);
    }
    s = __shfl(s, 0); q = __shfl(q, 0);
    const float mean = s * (1.f / ND);
    const float var  = q * (1.f / ND) - mean * mean;
    const float rs   = rsqrtf(var + 1e-5f);

    float4 g0 = *(const float4*)(g + d);
    float4 g1 = *(const float4*)(g + d + 4);
    float4 b0 = *(const float4*)(b + d);
    float4 b1 = *(const float4*)(b + d + 4);
    float4 o0, o1;
    o0.x = (v0.x - mean) * rs * g0.x + b0.x;
    o0.y = (v0.y - mean) * rs * g0.y + b0.y;
    o0.z = (v0.z - mean) * rs * g0.z + b0.z;
    o0.w = (v0.w - mean) * rs * g0.w + b0.w;
    o1.x = (v1.x - mean) * rs * g1.x + b1.x;
    o1.y = (v1.y - mean) * rs * g1.y + b1.y;
    o1.z = (v1.z - mean) * rs * g1.z + b1.z;
    o1.w = (v1.w - mean) * rs * g1.w + b1.w;
    if (relu) {
        o0.x = fmaxf(o0.x, 0.f); o0.y = fmaxf(o0.y, 0.f);
        o0.z = fmaxf(o0.z, 0.f); o0.w = fmaxf(o0.w, 0.f);
        o1.x = fmaxf(o1.x, 0.f); o1.y = fmaxf(o1.y, 0.f);
        o1.z = fmaxf(o1.z, 0.f); o1.w = fmaxf(o1.w, 0.f);
    }
    float* y = Y + (size_t)row * ND;
    *(float4*)(y + d)     = o0;
    *(float4*)(y + d + 4) = o1;
}

__global__ __launch_bounds__(256) void sqnorm_kernel(
    const float* __restrict__ X, float* __restrict__ sq)
{
    const int lane = threadIdx.x & 63;
    const int row  = blockIdx.x * 4 + (threadIdx.x >> 6);
    const float* x = X + (size_t)row * ND;
    const int d = lane * 8;
    float4 v0 = *(const float4*)(x + d);
    float4 v1 = *(const float4*)(x + d + 4);
    float q = v0.x*v0.x + v0.y*v0.y + v0.z*v0.z + v0.w*v0.w
            + v1.x*v1.x + v1.y*v1.y + v1.z*v1.z + v1.w*v1.w;
#pragma unroll
    for (int off = 32; off; off >>= 1) q += __shfl_down(q, off);
    if (lane == 0) sq[row] = q;
}

// ---------------------------------------------------------------------------
// Parallel exact top-96 radix select (multi-block per row).
// fkey: order-preserving f32 -> u32 map.
// ---------------------------------------------------------------------------
__device__ __forceinline__ unsigned fkey(float f)
{
    unsigned u = __float_as_uint(f);
    return (u & 0x80000000u) ? ~u : (u | 0x80000000u);
}

__global__ __launch_bounds__(256) void topk_init(
    unsigned* __restrict__ Hist, unsigned* __restrict__ Pref,
    int* __restrict__ Krem, int* __restrict__ cA, int* __restrict__ cB)
{
    const int b = blockIdx.x;
    Hist[(size_t)b * 256 + threadIdx.x] = 0u;
    if (threadIdx.x == 0) { Pref[b] = 0u; Krem[b] = NC; cA[b] = 0; cB[b] = 0; }
}

__global__ __launch_bounds__(256) void topk_hist(
    const float* __restrict__ S, const unsigned* __restrict__ Pref,
    unsigned* __restrict__ Hist, int b0, int level)
{
    const int r = blockIdx.y;
    const int b = b0 + r;
    const float* p = S + (size_t)r * NN + blockIdx.x * TK_SEG;
    __shared__ unsigned h[256];
    h[threadIdx.x] = 0u;
    __syncthreads();
    const int shift = 24 - 8 * level;
    const unsigned pref = Pref[b];
    const unsigned pmask = level ? (0xFFFFFFFFu << (shift + 8)) : 0u;
    for (int i = threadIdx.x; i < TK_SEG; i += 256) {
        unsigned u = fkey(p[i]);
        if ((u & pmask) == pref)
            atomicAdd(&h[(u >> shift) & 255u], 1u);
    }
    __syncthreads();
    unsigned c = h[threadIdx.x];
    if (c) atomicAdd(&Hist[(size_t)b * 256 + threadIdx.x], c);
}

__global__ __launch_bounds__(256) void topk_scan(
    unsigned* __restrict__ Hist, unsigned* __restrict__ Pref,
    int* __restrict__ Krem, int b0, int level)
{
    const int b = b0 + blockIdx.x;
    const int t = threadIdx.x;
    __shared__ unsigned s[256];
    const unsigned c = Hist[(size_t)b * 256 + t];
    s[t] = c;
    __syncthreads();
#pragma unroll
    for (int off = 1; off < 256; off <<= 1) {     // Hillis-Steele inclusive scan
        unsigned v = (t >= off) ? s[t - off] : 0u;
        __syncthreads();
        s[t] += v;
        __syncthreads();
    }
    const int krem = Krem[b];
    const int incl = (int)s[t];
    const int excl = incl - (int)c;
    if (excl < krem && incl >= krem) {
        Pref[b] |= ((unsigned)t) << (24 - 8 * level);
        Krem[b] = krem - excl;
    }
    Hist[(size_t)b * 256 + t] = 0u;               // re-zero for next level/chunk
}

__global__ __launch_bounds__(256) void topk_collect(
    const float* __restrict__ S, const unsigned* __restrict__ Pref,
    const int* __restrict__ Krem, int* __restrict__ cA, int* __restrict__ cB,
    int* __restrict__ idx_out, float* __restrict__ val_out, int b0)
{
    const int r = blockIdx.y;
    const int b = b0 + r;
    const int base = blockIdx.x * TK_SEG;
    const float* p = S + (size_t)r * NN + base;
    const unsigned T = Pref[b];
    const int need = Krem[b];
    const int cntLess = NC - need;
    for (int i = threadIdx.x; i < TK_SEG; i += 256) {
        unsigned u = fkey(p[i]);
        if (u < T) {
            int pos = atomicAdd(&cA[b], 1);
            idx_out[b * NC + pos] = base + i;
            val_out[b * NC + pos] = p[i];
        } else if (u == T) {
            int pos = atomicAdd(&cB[b], 1);
            if (pos < need) {
                idx_out[b * NC + cntLess + pos] = base + i;
                val_out[b * NC + cntLess + pos] = p[i];
            }
        }
    }
}

__global__ __launch_bounds__(128) void probs_kernel(
    const float* __restrict__ svals, float* __restrict__ probs)
{
    const int b = blockIdx.x;
    const int tid = threadIdx.x;
    __shared__ float red[128];
    const bool valid = tid < NC;
    float s = valid ? -svals[b * NC + tid] : -3.4e38f;
    red[tid] = s;
    __syncthreads();
#pragma unroll
    for (int off = 64; off; off >>= 1) {
        if (tid < off) red[tid] = fmaxf(red[tid], red[tid + off]);
        __syncthreads();
    }
    const float m = red[0];
    __syncthreads();
    float e = valid ? expf(s - m) : 0.f;
    red[tid] = e;
    __syncthreads();
#pragma unroll
    for (int off = 64; off; off >>= 1) {
        if (tid < off) red[tid] += red[tid + off];
        __syncthreads();
    }
    const float sum = red[0];
    if (valid) probs[b * NC + tid] = e / sum;
}

__global__ __launch_bounds__(256) void ctx_kernel(
    const float* __restrict__ VAL, const float* __restrict__ probs,
    const float* __restrict__ cand_y, const int* __restrict__ idx,
    const float* __restrict__ labW, const float* __restrict__ labb,
    const float* __restrict__ xin, float* __restrict__ xout, int b0)
{
    const int b_loc = blockIdx.x;
    const int b = b0 + b_loc;
    const int tid = threadIdx.x;
    __shared__ float pv[NC];
    __shared__ float red[256];
    float py_part = 0.f;
    if (tid < NC) {
        float p = probs[b * NC + tid];
        pv[tid] = p;
        py_part = p * cand_y[idx[b * NC + tid]];
    }
    red[tid] = py_part;
    __syncthreads();
#pragma unroll
    for (int off = 128; off; off >>= 1) {
        if (tid < off) red[tid] += red[tid + off];
        __syncthreads();
    }
    const float py = red[0];

    for (int d = tid; d < ND; d += 256) {
        const float* vp = VAL + (size_t)b_loc * NC * ND + d;
        float acc = 0.f;
#pragma unroll 8
        for (int c = 0; c < NC; c++) acc += pv[c] * vp[(size_t)c * ND];
        float ctx = acc + py * labW[d] + labb[d];
        xout[(size_t)b * ND + d] = xin[(size_t)b * ND + d] + ctx;
    }
}

__global__ __launch_bounds__(64) void head_kernel(
    const float* __restrict__ X, const float* __restrict__ hW,
    const float* __restrict__ hb, float* __restrict__ out)
{
    const int b = blockIdx.x;
    const int lane = threadIdx.x;
    const float* x = X + (size_t)b * ND;
    float acc = 0.f;
#pragma unroll
    for (int j = 0; j < 8; j++) {
        int d = lane + 64 * j;
        acc += x[d] * hW[d];
    }
#pragma unroll
    for (int off = 32; off; off >>= 1) acc += __shfl_down(acc, off);
    if (lane == 0) out[b] = acc + hb[0];
}

// ---------------------------------------------------------------------------
extern "C" void kernel_launch(void* const* d_in, const int* in_sizes, int n_in,
                              void* d_out, int out_size, void* d_ws, size_t ws_size,
                              hipStream_t stream)
{
    const float* x_num    = (const float*)d_in[0];
    const float* cand_num = (const float*)d_in[1];
    const float* cand_y   = (const float*)d_in[2];
    const float* lin_W    = (const float*)d_in[3];
    const float* lin_b    = (const float*)d_in[4];
    const float* e_W1     = (const float*)d_in[5];
    const float* e_b1     = (const float*)d_in[6];
    const float* e_W2     = (const float*)d_in[7];
    const float* e_b2     = (const float*)d_in[8];
    const float* mix_g    = (const float*)d_in[9];
    const float* mix_b    = (const float*)d_in[10];
    const float* K_W      = (const float*)d_in[11];
    const float* K_b      = (const float*)d_in[12];
    const float* lab_W    = (const float*)d_in[13];
    const float* lab_b    = (const float*)d_in[14];
    const float* T_W1     = (const float*)d_in[15];
    const float* T_b1     = (const float*)d_in[16];
    const float* T_W2     = (const float*)d_in[17];
    const float* p_ln_g   = (const float*)d_in[18];
    const float* p_ln_b   = (const float*)d_in[19];
    const float* p_W1     = (const float*)d_in[20];
    const float* p_b1     = (const float*)d_in[21];
    const float* p_W2     = (const float*)d_in[22];
    const float* p_b2     = (const float*)d_in[23];
    const float* h_ln_g   = (const float*)d_in[24];
    const float* h_ln_b   = (const float*)d_in[25];
    const float* h_W      = (const float*)d_in[26];
    const float* h_b      = (const float*)d_in[27];
    float* out = (float*)d_out;
    (void)in_sizes; (void)n_in; (void)out_size; (void)ws_size;

    // ---- workspace layout (~241 MB) ----
    size_t off = 0;
    auto alloc = [&](size_t floats) -> float* {
        float* p = (float*)((char*)d_ws + off);
        off += ((floats * 4 + 255) / 256) * 256;
        return p;
    };
    // transposed weights [N][K] f32
    float* WT_lin = alloc((size_t)ND * NF);
    float* WT_e1  = alloc((size_t)NDB * ND);
    float* WT_e2  = alloc((size_t)ND * NDB);
    float* WT_kw  = alloc((size_t)ND * ND);
    float* WT_t1  = alloc((size_t)NDB * ND);
    float* WT_t2  = alloc((size_t)ND * NDB);
    float* WT_p1  = alloc((size_t)NDB * ND);
    float* WT_p2  = alloc((size_t)ND * NDB);

    float* R_CK  = alloc((size_t)NN * ND);        // cand_k (persistent)
    float* R_sq  = alloc(NN);
    float* R_Hx  = alloc((size_t)NB * ND);
    float* R_Tx  = alloc((size_t)NB * NDB);
    float* R_Gx  = alloc((size_t)NB * ND);
    float* R_kx  = alloc((size_t)NB * ND);
    int*   R_idx = (int*)alloc((size_t)NB * NC);
    float* R_ssel= alloc((size_t)NB * NC);
    float* R_prob= alloc((size_t)NB * NC);
    float* R_xupd= alloc((size_t)NB * ND);
    float* R_lnx = alloc((size_t)NB * ND);
    float* R_tp  = alloc((size_t)NB * NDB);
    float* R_x2  = alloc((size_t)NB * ND);
    float* R_lnx2= alloc((size_t)NB * ND);
    // topk aux
    unsigned* TK_hist = (unsigned*)alloc((size_t)NB * 256);
    unsigned* TK_pref = (unsigned*)alloc(NB);
    int*      TK_krem = (int*)alloc(NB);
    int*      TK_cA   = (int*)alloc(NB);
    int*      TK_cB   = (int*)alloc(NB);
    float* SCR   = alloc((size_t)BB_C * NN);      // 67 MB shared scratch

    // ---- 0. transpose weights + topk init ----
    auto tr = [&](const float* W, float* WT, int K, int N) {
        transpose_kernel<<<dim3((K * N + 255) / 256), dim3(256), 0, stream>>>(W, WT, K, N);
    };
    tr(lin_W, WT_lin, NF, ND);
    tr(e_W1,  WT_e1,  ND, NDB);
    tr(e_W2,  WT_e2,  NDB, ND);
    tr(K_W,   WT_kw,  ND, ND);
    tr(T_W1,  WT_t1,  ND, NDB);
    tr(T_W2,  WT_t2,  NDB, ND);
    tr(p_W1,  WT_p1,  ND, NDB);
    tr(p_W2,  WT_p2,  NDB, ND);
    topk_init<<<dim3(NB), dim3(256), 0, stream>>>(TK_hist, TK_pref, TK_krem, TK_cA, TK_cB);

    auto gsplit = [&](const float* A, const float* BT, const float* bias,
                      const float* res, const float* sq, float* C,
                      int M, int Nn, int K, int relu) {
        gemm_split_nt<<<dim3(Nn / 128, M / 128), dim3(256), 0, stream>>>(
            A, BT, bias, res, sq, C, M, Nn, K, relu);
    };

    // ---- 1. candidate encode (chunked, split-bf16 MFMA) ----
    for (int n0 = 0; n0 < NN; n0 += CH_A) {
        float* H = SCR;                          // [CH_A, 512]
        float* T = SCR + (size_t)CH_A * ND;      // [CH_A, 1024]; reused as G
        gsplit(cand_num + (size_t)n0 * NF, WT_lin, lin_b, nullptr, nullptr, H, CH_A, ND, NF, 0);
        gsplit(H, WT_e1, e_b1, nullptr, nullptr, T, CH_A, NDB, ND, 1);
        gsplit(T, WT_e2, e_b2, H, nullptr, H, CH_A, ND, NDB, 0);
        ln_kernel<<<dim3(CH_A / 4), dim3(256), 0, stream>>>(H, mix_g, mix_b, T, 0);
        gsplit(T, WT_kw, K_b, nullptr, nullptr, R_CK + (size_t)n0 * ND, CH_A, ND, ND, 0);
        sqnorm_kernel<<<dim3(CH_A / 4), dim3(256), 0, stream>>>(
            R_CK + (size_t)n0 * ND, R_sq + n0);
    }

    // ---- 2. x encode (split-bf16 MFMA) ----
    gsplit(x_num, WT_lin, lin_b, nullptr, nullptr, R_Hx, NB, ND, NF, 0);
    gsplit(R_Hx, WT_e1, e_b1, nullptr, nullptr, R_Tx, NB, NDB, ND, 1);
    gsplit(R_Tx, WT_e2, e_b2, R_Hx, nullptr, R_Hx, NB, ND, NDB, 0);
    ln_kernel<<<dim3(NB / 4), dim3(256), 0, stream>>>(R_Hx, mix_g, mix_b, R_Gx, 0);
    gsplit(R_Gx, WT_kw, K_b, nullptr, nullptr, R_kx, NB, ND, ND, 0);

    // ---- 3. scores (split-bf16 MFMA) + parallel top-96 + softmax ----
    for (int b0 = 0; b0 < NB; b0 += BB_C) {
        gsplit(R_kx + (size_t)b0 * ND, R_CK, nullptr, nullptr, R_sq, SCR,
               BB_C, NN, ND, 0);
        for (int level = 0; level < 4; level++) {
            topk_hist<<<dim3(TK_SPLIT, BB_C), dim3(256), 0, stream>>>(
                SCR, TK_pref, TK_hist, b0, level);
            topk_scan<<<dim3(BB_C), dim3(256), 0, stream>>>(
                TK_hist, TK_pref, TK_krem, b0, level);
        }
        topk_collect<<<dim3(TK_SPLIT, BB_C), dim3(256), 0, stream>>>(
            SCR, TK_pref, TK_krem, TK_cA, TK_cB, R_idx, R_ssel, b0);
    }
    probs_kernel<<<dim3(NB), dim3(128), 0, stream>>>(R_ssel, R_prob);

    // ---- 4. values path (plain bf16 MFMA, diff fused) ----
    for (int b0 = 0; b0 < NB; b0 += BB_D) {
        unsigned short* TT = (unsigned short*)SCR;               // [M,1024] bf16
        float* VAL = SCR + (size_t)BB_D * NC * NDB / 2 + 64;     // f32 after TT
        const int M = BB_D * NC;   // 12288
        gemm_diff_bf16<<<dim3(NDB / 128, M / 128), dim3(256), 0, stream>>>(
            R_kx + (size_t)b0 * ND, R_CK, R_idx + b0 * NC, WT_t1, T_b1,
            TT, M, NDB, ND);
        gemm_bf16_f32<<<dim3(ND / 128, M / 128), dim3(256), 0, stream>>>(
            TT, WT_t2, VAL, M, ND, NDB);
        ctx_kernel<<<dim3(BB_D), dim3(256), 0, stream>>>(
            VAL, R_prob, cand_y, R_idx, lab_W, lab_b, R_Hx, R_xupd, b0);
    }

    // ---- 5. predictor block + head (split-bf16 MFMA) ----
    ln_kernel<<<dim3(NB / 4), dim3(256), 0, stream>>>(R_xupd, p_ln_g, p_ln_b, R_lnx, 0);
    gsplit(R_lnx, WT_p1, p_b1, nullptr, nullptr, R_tp, NB, NDB, ND, 1);
    gsplit(R_tp, WT_p2, p_b2, R_xupd, nullptr, R_x2, NB, ND, NDB, 0);
    ln_kernel<<<dim3(NB / 4), dim3(256), 0, stream>>>(R_x2, h_ln_g, h_ln_b, R_lnx2, 1);
    head_kernel<<<dim3(NB), dim3(64), 0, stream>>>(R_lnx2, h_W, h_b, out);
}